// Round 1
// baseline (81.540 us; speedup 1.0000x reference)
//
#include <hip/hip_runtime.h>

#define KN 8192

// Monotone float -> uint64 (value, index) key; lexicographic order == stable
// argsort order. 64-bit required: ~1 expected f32 value collision among 8192
// N(0,1) samples, and duplicate ranks would break the scatter.
__device__ __forceinline__ unsigned long long make_key(float x, int idx) {
    unsigned int u = __float_as_uint(x);
    u ^= (unsigned int)((int)u >> 31) | 0x80000000u;  // neg: flip all; pos: set sign
    return ((unsigned long long)u << 13) | (unsigned int)idx;
}

// ---------------------------------------------------------------------------
// Kernel 1: partial ranks, brute force, NO atomics.
// rank[u] = #{ v : key[v] < key[u] }  (keys distinct)
// grid = 8 u-tiles x 32 v-tiles x 2 arrays = 512 blocks of 256 threads.
// Per block: 1024 u (4/thread) x 256 v.  Partials: 2 MiB (was 4 MiB).
// ---------------------------------------------------------------------------
constexpr int UT  = 1024;        // u per block
constexpr int VC  = 256;         // v per block
constexpr int NVT = KN / VC;     // 32 v-tiles

__global__ __launch_bounds__(256) void rank_partial(const float* __restrict__ X,
                                                    const float* __restrict__ Xh,
                                                    int* __restrict__ part) {
    int blk = blockIdx.x;
    int arr = blk & 1;
    int vt  = (blk >> 1) & (NVT - 1);
    int ut  = blk >> 6;                       // blk / (2*NVT), 0..7
    const float* src = arr ? Xh : X;

    int tid = threadIdx.x;
    int u0 = ut * UT + tid;

    unsigned long long ku0 = make_key(src[u0],       u0);
    unsigned long long ku1 = make_key(src[u0 + 256], u0 + 256);
    unsigned long long ku2 = make_key(src[u0 + 512], u0 + 512);
    unsigned long long ku3 = make_key(src[u0 + 768], u0 + 768);

    __shared__ __align__(16) unsigned long long tile[VC];
    {
        int v = vt * VC + tid;
        tile[tid] = make_key(src[v], v);
    }
    __syncthreads();

    const ulonglong2* t2 = (const ulonglong2*)tile;
    int c0 = 0, c1 = 0, c2 = 0, c3 = 0;
#pragma unroll 8
    for (int j = 0; j < VC / 2; ++j) {
        ulonglong2 kv = t2[j];              // wave-uniform -> ds_read_b128 broadcast
        c0 += (kv.x < ku0) + (kv.y < ku0);
        c1 += (kv.x < ku1) + (kv.y < ku1);
        c2 += (kv.x < ku2) + (kv.y < ku2);
        c3 += (kv.x < ku3) + (kv.y < ku3);
    }

    int base = (arr * NVT + vt) * KN + u0;   // disjoint per block, coalesced
    part[base]       = c0;
    part[base + 256] = c1;
    part[base + 512] = c2;
    part[base + 768] = c3;
}

// ---------------------------------------------------------------------------
// Kernel 2: reduce partials -> rank, scatter argsort sequences in-place:
//   a[rank_a[u]] = u ; b[rank_b[u]] = u.
// Also zero-inits the packed atomic accumulator for kernel 3 (kernel-boundary
// ordering on the stream makes the store visible to K3's atomics).
// grid = 64 blocks x 256  (threads 0..8191 -> array a, 8192..16383 -> b)
// ---------------------------------------------------------------------------
__global__ __launch_bounds__(256) void reduce_scatter(const int* __restrict__ part,
                                                      int* __restrict__ a,
                                                      int* __restrict__ b,
                                                      unsigned long long* __restrict__ acc) {
    int t = blockIdx.x * 256 + threadIdx.x;   // 0..16383
    if (t == 0) *acc = 0ULL;
    int arr = t >> 13;
    int u   = t & (KN - 1);

    const int* p = part + (arr * NVT) * KN + u;
    int r = 0;
#pragma unroll
    for (int vt = 0; vt < NVT; ++vt) r += p[vt * KN];   // 32 loads, all in flight

    if (arr == 0) a[r] = u; else b[r] = u;
}

// ---------------------------------------------------------------------------
// Kernel 3: ndisordered = sum over ALL ordered position pairs (k,l) of
//   (a[k]<a[l]) != (b[k]<b[l]).
// This IS the reference's full boolean-matrix sum (diagonal contributes 0),
// so no gather_e / inv_count / x2 needed. Full matrix, no triangular decode.
// grid = 8 k-tiles(1024, 4/thread) x 64 l-tiles(128) = 512 blocks x 256 thr.
// Finalize fused: packed u64 atomic {blocks_done:24 | count:40}; the last
// block owns the total and writes out.
// ---------------------------------------------------------------------------
constexpr int KT    = 1024;            // k per block (4 per thread)
constexpr int LT    = 128;             // l per block (LDS tile)
constexpr int NLT   = KN / LT;         // 64
constexpr int NBLK3 = (KN / KT) * NLT; // 512

__global__ __launch_bounds__(256) void pair_count(const int* __restrict__ a,
                                                  const int* __restrict__ b,
                                                  unsigned long long* __restrict__ acc,
                                                  float* __restrict__ out) {
    int blk = blockIdx.x;
    int lt  = blk & (NLT - 1);
    int kt  = blk >> 6;
    int tid = threadIdx.x;

    __shared__ int2 tl[LT];
    __shared__ int wsum[4];
    if (tid < LT) {
        int l = lt * LT + tid;
        tl[tid] = make_int2(a[l], b[l]);
    }
    int k0  = kt * KT + tid;
    int ak0 = a[k0], ak1 = a[k0 + 256], ak2 = a[k0 + 512], ak3 = a[k0 + 768];
    int bk0 = b[k0], bk1 = b[k0 + 256], bk2 = b[k0 + 512], bk3 = b[k0 + 768];
    __syncthreads();

    int c = 0;
#pragma unroll 8
    for (int j = 0; j < LT; ++j) {
        int2 v = tl[j];                      // wave-uniform -> ds_read_b64 broadcast
        c += (ak0 < v.x) != (bk0 < v.y);
        c += (ak1 < v.x) != (bk1 < v.y);
        c += (ak2 < v.x) != (bk2 < v.y);
        c += (ak3 < v.x) != (bk3 < v.y);
    }

    for (int off = 32; off; off >>= 1) c += __shfl_down(c, off);
    if ((tid & 63) == 0) wsum[tid >> 6] = c;
    __syncthreads();
    if (tid == 0) {
        unsigned long long partial =
            (unsigned long long)(wsum[0] + wsum[1] + wsum[2] + wsum[3]);
        // max partial = 1024*128 = 2^17; max total = 8192*8191 < 2^40.
        unsigned long long old = atomicAdd(acc, (1ULL << 40) | partial);
        if ((old >> 40) == (unsigned long long)(NBLK3 - 1)) {
            unsigned long long total = (old & ((1ULL << 40) - 1)) + partial;
            // 8192*8191 = 67100672 is exactly representable in f32;
            // (float)total matches jnp's int->float32 round-to-nearest.
            out[0] = (float)total / 67100672.0f;
        }
    }
}

// ---------------------------------------------------------------------------
// Workspace layout (bytes). Every word is written before it is read, so the
// harness 0xAA poison needs no memset.
//   0        : part[2*32*8192] int   (2 MiB)
//   2097152  : a[8192] int
//   2129920  : b[8192] int
//   2162688  : acc (unsigned long long, 8B, zeroed by reduce_scatter)
// total ~2.07 MiB
// ---------------------------------------------------------------------------
extern "C" void kernel_launch(void* const* d_in, const int* in_sizes, int n_in,
                              void* d_out, int out_size, void* d_ws, size_t ws_size,
                              hipStream_t stream) {
    const float* X  = (const float*)d_in[0];
    const float* Xh = (const float*)d_in[1];

    char* ws = (char*)d_ws;
    int* part = (int*)(ws);
    int* a    = (int*)(ws + 2097152);
    int* b    = (int*)(ws + 2129920);
    unsigned long long* acc = (unsigned long long*)(ws + 2162688);

    rank_partial  <<<dim3(512), dim3(256), 0, stream>>>(X, Xh, part);
    reduce_scatter<<<dim3(64),  dim3(256), 0, stream>>>(part, a, b, acc);
    pair_count    <<<dim3(512), dim3(256), 0, stream>>>(a, b, acc, (float*)d_out);
}

// Round 2
// 78.525 us; speedup vs baseline: 1.0384x; 1.0384x over previous
//
#include <hip/hip_runtime.h>

#define KN 8192

// Monotone float -> uint64 (value, index) key; lexicographic order == stable
// argsort order. 64-bit required: ~1 expected f32 value collision among 8192
// N(0,1) samples, and duplicate ranks would break the scatter.
__device__ __forceinline__ unsigned long long make_key(float x, int idx) {
    unsigned int u = __float_as_uint(x);
    u ^= (unsigned int)((int)u >> 31) | 0x80000000u;  // neg: flip all; pos: set sign
    return ((unsigned long long)u << 13) | (unsigned int)idx;
}

// ---------------------------------------------------------------------------
// Kernel 1: partial ranks, brute force, NO atomics.
// rank[u] = #{ v : key[v] < key[u] }  (keys distinct)
// grid = 16 u-tiles x 32 v-tiles x 2 arrays = 1024 blocks of 256 threads
// (4 blocks/CU -> 4 waves/SIMD: latency-hiding restored vs the 512-block try).
// Per block: 512 u (2/thread) x 256 v. Partials stay at 2 MiB.
// ---------------------------------------------------------------------------
constexpr int UT  = 512;         // u per block (2 per thread)
constexpr int VC  = 256;         // v per block
constexpr int NVT = KN / VC;     // 32 v-tiles

__global__ __launch_bounds__(256) void rank_partial(const float* __restrict__ X,
                                                    const float* __restrict__ Xh,
                                                    int* __restrict__ part) {
    int blk = blockIdx.x;
    int arr = blk & 1;
    int vt  = (blk >> 1) & (NVT - 1);
    int ut  = blk >> 6;                       // 0..15
    const float* src = arr ? Xh : X;

    int tid = threadIdx.x;
    int u0 = ut * UT + tid;

    unsigned long long ku0 = make_key(src[u0],       u0);
    unsigned long long ku1 = make_key(src[u0 + 256], u0 + 256);

    __shared__ __align__(16) unsigned long long tile[VC];
    {
        int v = vt * VC + tid;
        tile[tid] = make_key(src[v], v);
    }
    __syncthreads();

    const ulonglong2* t2 = (const ulonglong2*)tile;
    int c0 = 0, c1 = 0;
#pragma unroll 8
    for (int j = 0; j < VC / 2; ++j) {
        ulonglong2 kv = t2[j];              // wave-uniform -> ds_read_b128 broadcast
        c0 += (kv.x < ku0) + (kv.y < ku0);
        c1 += (kv.x < ku1) + (kv.y < ku1);
    }

    int base = (arr * NVT + vt) * KN + u0;   // disjoint per block, coalesced
    part[base]       = c0;
    part[base + 256] = c1;
}

// ---------------------------------------------------------------------------
// Kernel 2: reduce partials -> rank, scatter argsort sequences in-place:
//   a[rank_a[u]] = u ; b[rank_b[u]] = u.
// Also zero-inits the packed atomic accumulator for kernel 3 (kernel-boundary
// ordering on the stream makes the store visible to K3's atomics).
// grid = 64 blocks x 256  (threads 0..8191 -> array a, 8192..16383 -> b)
// ---------------------------------------------------------------------------
__global__ __launch_bounds__(256) void reduce_scatter(const int* __restrict__ part,
                                                      int* __restrict__ a,
                                                      int* __restrict__ b,
                                                      unsigned long long* __restrict__ acc) {
    int t = blockIdx.x * 256 + threadIdx.x;   // 0..16383
    if (t == 0) *acc = 0ULL;
    int arr = t >> 13;
    int u   = t & (KN - 1);

    const int* p = part + (arr * NVT) * KN + u;
    int r = 0;
#pragma unroll
    for (int vt = 0; vt < NVT; ++vt) r += p[vt * KN];   // 32 loads, all in flight

    if (arr == 0) a[r] = u; else b[r] = u;
}

// ---------------------------------------------------------------------------
// Kernel 3: D = sum over position pairs k<l of (a[k]<a[l]) != (b[k]<b[l]);
// ndisordered = 2*D (the reference's full boolean matrix is symmetric with
// zero diagonal). Triangular 256x256 tiles: 32*33/2 = 528 blocks -- half the
// compare work of the full-matrix variant that regressed round 1.
// Finalize fused: packed u64 atomic {blocks_done:24 | count:40}; the last
// block owns the total and writes out.
// ---------------------------------------------------------------------------
constexpr int TS    = 256;
constexpr int T     = KN / TS;          // 32
constexpr int NBLK3 = T * (T + 1) / 2;  // 528

__global__ __launch_bounds__(256) void pair_count(const int* __restrict__ a,
                                                  const int* __restrict__ b,
                                                  unsigned long long* __restrict__ acc,
                                                  float* __restrict__ out) {
    int blk = blockIdx.x;
    int p = 0, rem = blk;
    while (rem >= T - p) { rem -= T - p; ++p; }   // wave-uniform decode
    int q = p + rem;                              // p <= q
    int tid = threadIdx.x;

    __shared__ __align__(16) int2 tl[TS];
    __shared__ int wsum[4];

    int k  = p * TS + tid;
    int ak = a[k], bk = b[k];
    int l  = q * TS + tid;
    tl[tid] = make_int2(a[l], b[l]);
    __syncthreads();

    int c = 0;
    if (p == q) {
        for (int j = tid + 1; j < TS; ++j) {      // strict upper triangle
            int2 v = tl[j];
            c += (ak < v.x) != (bk < v.y);
        }
    } else {
        const int4* t4 = (const int4*)tl;
#pragma unroll 8
        for (int j = 0; j < TS / 2; ++j) {
            int4 v = t4[j];                       // wave-uniform -> b128 broadcast
            c += (ak < v.x) != (bk < v.y);
            c += (ak < v.z) != (bk < v.w);
        }
    }

    for (int off = 32; off; off >>= 1) c += __shfl_down(c, off);
    if ((tid & 63) == 0) wsum[tid >> 6] = c;
    __syncthreads();
    if (tid == 0) {
        unsigned long long partial =
            (unsigned long long)(wsum[0] + wsum[1] + wsum[2] + wsum[3]);
        // max partial = 256*256 = 2^16; max D < 2^26 -- fits the 40-bit field.
        unsigned long long old = atomicAdd(acc, (1ULL << 40) | partial);
        if ((old >> 40) == (unsigned long long)(NBLK3 - 1)) {
            unsigned long long D = (old & ((1ULL << 40) - 1)) + partial;
            // 2*D <= 8192*8191 = 67100672; (float)(2*D) is the same RNE
            // rounding jnp applies in astype(float32). Denominator exact.
            out[0] = (float)(2ULL * D) / 67100672.0f;
        }
    }
}

// ---------------------------------------------------------------------------
// Workspace layout (bytes). Every word is written before it is read, so the
// harness 0xAA poison needs no memset.
//   0        : part[2*32*8192] int   (2 MiB)
//   2097152  : a[8192] int
//   2129920  : b[8192] int
//   2162688  : acc (unsigned long long, 8B, zeroed by reduce_scatter)
// total ~2.07 MiB
// ---------------------------------------------------------------------------
extern "C" void kernel_launch(void* const* d_in, const int* in_sizes, int n_in,
                              void* d_out, int out_size, void* d_ws, size_t ws_size,
                              hipStream_t stream) {
    const float* X  = (const float*)d_in[0];
    const float* Xh = (const float*)d_in[1];

    char* ws = (char*)d_ws;
    int* part = (int*)(ws);
    int* a    = (int*)(ws + 2097152);
    int* b    = (int*)(ws + 2129920);
    unsigned long long* acc = (unsigned long long*)(ws + 2162688);

    rank_partial  <<<dim3(1024), dim3(256), 0, stream>>>(X, Xh, part);
    reduce_scatter<<<dim3(64),   dim3(256), 0, stream>>>(part, a, b, acc);
    pair_count    <<<dim3(528),  dim3(256), 0, stream>>>(a, b, acc, (float*)d_out);
}